// Round 1
// baseline (914.260 us; speedup 1.0000x reference)
//
#include <hip/hip_runtime.h>
#include <cstdint>

// Problem constants (B=1, S=2048, D=4096, H=32, HD=128)
#define S_LEN   2048
#define D_MODEL 4096
#define NHEAD   32
#define HDIM    128
#define LDQKV   12288  // 3*D

typedef __bf16 bf16x8 __attribute__((ext_vector_type(8)));
typedef float  f32x4  __attribute__((ext_vector_type(4)));
typedef unsigned short u16;
typedef unsigned int   u32;

union U16x8 { u16 u[8]; uint4 v; };

static __device__ __forceinline__ u16 f2b(float f) {
  u32 u = __builtin_bit_cast(u32, f);
  u += 0x7fffu + ((u >> 16) & 1u);   // RNE
  return (u16)(u >> 16);
}
static __device__ __forceinline__ float b2f(u16 h) {
  u32 u = ((u32)h) << 16;
  return __builtin_bit_cast(float, u);
}

// async global->LDS, 16B per lane; LDS dest is wave-uniform base + lane*16
#define GLOAD_LDS16(gp, lp)                                                   \
  __builtin_amdgcn_global_load_lds(                                           \
      (const __attribute__((address_space(1))) unsigned int*)(gp),            \
      (__attribute__((address_space(3))) unsigned int*)(lp), 16, 0, 0)

// ---------------- fp32 -> bf16 straight convert (hidden states) -------------
__global__ __launch_bounds__(256) void convert_f32_bf16(
    const float* __restrict__ in, u16* __restrict__ out) {
  size_t i = (size_t)blockIdx.x * 256 + threadIdx.x;   // 8 elems per thread
  const float4* p = (const float4*)in;
  float4 a = p[2 * i], b = p[2 * i + 1];
  U16x8 r;
  r.u[0] = f2b(a.x); r.u[1] = f2b(a.y); r.u[2] = f2b(a.z); r.u[3] = f2b(a.w);
  r.u[4] = f2b(b.x); r.u[5] = f2b(b.y); r.u[6] = f2b(b.z); r.u[7] = f2b(b.w);
  *(uint4*)(out + 8 * i) = r.v;
}

// ---------------- fp32 [R][C] -> bf16 [C][R] transpose+convert ---------------
// LDS stride 65: write idx mod 64 = 4*(tid&15)+(tid>>4)+... bijective per wave;
// read idx mod 64 = 8*(tid&7)+(tid>>3)+... bijective -> both conflict-free.
__global__ __launch_bounds__(256) void tconv(
    const float* __restrict__ in, u16* __restrict__ out, int R, int C) {
  __shared__ u16 tile[64][65];
  const int r0 = blockIdx.y * 64, c0 = blockIdx.x * 64;
  const int tid = threadIdx.x;
  const int tr = tid >> 4, tc = (tid & 15) * 4;
#pragma unroll
  for (int p = 0; p < 4; ++p) {
    float4 v = *(const float4*)(in + (size_t)(r0 + p * 16 + tr) * C + c0 + tc);
    u16* t = &tile[p * 16 + tr][tc];
    t[0] = f2b(v.x); t[1] = f2b(v.y); t[2] = f2b(v.z); t[3] = f2b(v.w);
  }
  __syncthreads();
  const int oc = tid >> 3, os = (tid & 7) * 8;
#pragma unroll
  for (int p = 0; p < 2; ++p) {
    U16x8 u;
#pragma unroll
    for (int j = 0; j < 8; ++j) u.u[j] = tile[os + j][p * 32 + oc];
    *(uint4*)(out + (size_t)(c0 + p * 32 + oc) * R + r0 + os) = u.v;
  }
}

// ---------------- bf16 GEMM: C[M][N] = A[M][K] * Bt[N][K]^T -----------------
// 128x128 block tile, BK=64, 4 waves (2x2), each wave 64x64 via 4x4 16x16x32 MFMA.
// Staging: global_load_lds width 16, XOR-swizzled chunks (slot = chunk^(row&7)).
template <typename OutT>
__global__ __launch_bounds__(256) void gemm_bt(
    const u16* __restrict__ A, const u16* __restrict__ Bt, OutT* __restrict__ C,
    int M, int N, int K) {
  __shared__ __align__(16) u16 As[128 * 64];
  __shared__ __align__(16) u16 Bs[128 * 64];
  const int tid = threadIdx.x;
  const int lane = tid & 63, wave = tid >> 6;
  const int lane15 = lane & 15, quad = lane >> 4;
  const int wm = (wave >> 1) * 64, wn = (wave & 1) * 64;
  const size_t bm = (size_t)blockIdx.y * 128, bn = (size_t)blockIdx.x * 128;
  const int sreg_row = lane >> 3;   // row within an 8-row region
  const int schunk = lane & 7;      // LDS chunk slot this lane fills

  f32x4 acc[4][4] = {};

  for (int k0 = 0; k0 < K; k0 += 64) {
#pragma unroll
    for (int i = 0; i < 4; ++i) {
      const int reg = wave * 4 + i;           // 16 regions of 8 rows
      const int row = reg * 8 + sreg_row;
      const int gc = schunk ^ (row & 7);      // global 16B-chunk to fetch
      GLOAD_LDS16(A + (bm + row) * (size_t)K + k0 + gc * 8, &As[reg * 512]);
      GLOAD_LDS16(Bt + (bn + row) * (size_t)K + k0 + gc * 8, &Bs[reg * 512]);
    }
    __syncthreads();
#pragma unroll
    for (int kk = 0; kk < 64; kk += 32) {
      const int cb = kk >> 3;
      bf16x8 af[4], bfr[4];
#pragma unroll
      for (int mt = 0; mt < 4; ++mt) {
        const int row = wm + mt * 16 + lane15;
        af[mt] = *(const bf16x8*)&As[row * 64 + (((cb + quad) ^ (lane15 & 7)) * 8)];
      }
#pragma unroll
      for (int nt = 0; nt < 4; ++nt) {
        const int row = wn + nt * 16 + lane15;
        bfr[nt] = *(const bf16x8*)&Bs[row * 64 + (((cb + quad) ^ (lane15 & 7)) * 8)];
      }
#pragma unroll
      for (int mt = 0; mt < 4; ++mt)
#pragma unroll
        for (int nt = 0; nt < 4; ++nt)
          acc[mt][nt] = __builtin_amdgcn_mfma_f32_16x16x32_bf16(
              af[mt], bfr[nt], acc[mt][nt], 0, 0, 0);
    }
    __syncthreads();
  }
  // C/D layout: col = lane&15, row = quad*4 + reg  [m89/m91 verified]
#pragma unroll
  for (int mt = 0; mt < 4; ++mt)
#pragma unroll
    for (int r = 0; r < 4; ++r) {
      size_t row = bm + wm + mt * 16 + quad * 4 + r;
#pragma unroll
      for (int nt = 0; nt < 4; ++nt) {
        size_t col = bn + wn + nt * 16 + lane15;
        float v = acc[mt][nt][r];
        if constexpr (sizeof(OutT) == 2) C[row * N + col] = (OutT)f2b(v);
        else                             C[row * N + col] = v;
      }
    }
}

// ---------------- RoPE in-place on Q,K of qkv [S][3D] -----------------------
__global__ __launch_bounds__(256) void rope_kernel(u16* __restrict__ qkv) {
  int idx = blockIdx.x * 256 + threadIdx.x;  // S*2048 pair-threads
  int s = idx >> 11;
  int p = idx & 2047;
  int h = p >> 6, j = p & 63;
  float freq = exp2f(-(float)j * 0.20762050593046015f);  // 10000^(-j/64)
  float ang = (float)s * freq;
  // native sin/cos: arg <= 2048 rad -> rev error ~1e-4 rad << bf16 quantization
  float sn = __sinf(ang), cs = __cosf(ang);
  size_t base = (size_t)s * LDQKV + h * HDIM + 2 * j;
  u32 q = *(const u32*)(qkv + base);
  float q0 = b2f((u16)(q & 0xffff)), q1 = b2f((u16)(q >> 16));
  u32 qo = (u32)f2b(q0 * cs - q1 * sn) | ((u32)f2b(q0 * sn + q1 * cs) << 16);
  *(u32*)(qkv + base) = qo;
  u32 k = *(const u32*)(qkv + base + D_MODEL);
  float k0 = b2f((u16)(k & 0xffff)), k1 = b2f((u16)(k >> 16));
  u32 ko = (u32)f2b(k0 * cs - k1 * sn) | ((u32)f2b(k0 * sn + k1 * cs) << 16);
  *(u32*)(qkv + base + D_MODEL) = ko;
}

// ---------------- V section of qkv -> vt[h][d][s] ---------------------------
// LDS stride 65, scalar u16 writes+reads: both bijective mod 64 -> conflict-free.
__global__ __launch_bounds__(256) void transpose_v(
    const u16* __restrict__ qkv, u16* __restrict__ vt) {
  __shared__ u16 tile[64][65];
  const int s0 = blockIdx.x * 64, d0 = blockIdx.y * 64, h = blockIdx.z;
  const int tid = threadIdx.x;
  const int tr = tid >> 3, tc = (tid & 7) * 8;
#pragma unroll
  for (int p = 0; p < 2; ++p) {
    U16x8 u;
    u.v = *(const uint4*)(qkv + (size_t)(s0 + p * 32 + tr) * LDQKV + 2 * D_MODEL +
                          h * HDIM + d0 + tc);
    u16* t = &tile[p * 32 + tr][tc];
#pragma unroll
    for (int j = 0; j < 8; ++j) t[j] = u.u[j];
  }
  __syncthreads();
  const int dd = tid >> 3, ss = (tid & 7) * 8;
#pragma unroll
  for (int p = 0; p < 2; ++p) {
    U16x8 u;
#pragma unroll
    for (int j = 0; j < 8; ++j) u.u[j] = tile[ss + j][p * 32 + dd];
    *(uint4*)(vt + (size_t)h * HDIM * S_LEN + (size_t)(d0 + p * 32 + dd) * S_LEN +
              s0 + ss) = u.v;
  }
}

// ---------------- Flash attention (non-causal, fixed-max softmax) -----------
// Block: 256 thr (4 waves), one head, 128 Q rows (32/wave, 2 m-frags).
// KV tiles of 64. T14 async-STAGE: next tile's K/V prefetched into registers
// right after the front barrier (HBM latency hides under QK^T/softmax/PV),
// then ds_write'd into the SAME XOR-swizzled LDS layout next iteration
// (base + lane*16B decomposes exactly as the old global_load_lds dest).
// T5: setprio(1) around MFMA clusters. Grid 16x32 = 512 = 2 blocks/CU resident.
__global__ __launch_bounds__(256, 2) void attn_kernel(
    const u16* __restrict__ qkv, const u16* __restrict__ vt, u16* __restrict__ ctx) {
  __shared__ __align__(16) u16 Ks[64 * 128];    // [kpos][d], XOR-swizzled 16B chunks
  __shared__ __align__(16) u16 Vs[128 * 64];    // [d][kpos], XOR-swizzled
  __shared__ __align__(16) u16 Ps[4][32 * 72];  // per-wave P, [q][kpos], stride 72
  const int h = blockIdx.y, qt = blockIdx.x;
  const int tid = threadIdx.x;
  const int lane = tid & 63, wave = tid >> 6;
  const int lane15 = lane & 15, quad = lane >> 4;
  const int q0 = qt * 128 + wave * 32;

  // Q A-frags in registers: A[m=lane&15][k=quad*8+j]  [m120 verified]
  bf16x8 aq[2][4];
#pragma unroll
  for (int mi = 0; mi < 2; ++mi)
#pragma unroll
    for (int kt = 0; kt < 4; ++kt)
      aq[mi][kt] = *(const bf16x8*)(qkv + (size_t)(q0 + mi * 16 + lane15) * LDQKV +
                                    h * HDIM + kt * 32 + quad * 8);

  f32x4 o[2][8] = {};
  float lsum[2][4] = {};

  const int krow_off = wave * 16 + (lane >> 4);  // + i*4
  const int kslot = lane & 15;
  const int vrow_off = wave * 32 + (lane >> 3);  // + i*8
  const int vslot = lane & 7;
  const u16* kbase = qkv + D_MODEL + h * HDIM;
  const u16* vbase = vt + (size_t)h * HDIM * S_LEN;
  const float cexp = 0.12751879523243985f;  // log2(e)/sqrt(128)

  // T14 staging registers: K tile 64x128 (4x uint4/thread), V tile 128x64.
  uint4 kreg[4], vreg[4];
#pragma unroll
  for (int i = 0; i < 4; ++i) {
    const int krow = krow_off + i * 4;            // 0..63
    const int kgc = kslot ^ (krow & 7);
    kreg[i] = *(const uint4*)(kbase + (size_t)krow * LDQKV + kgc * 8);
    const int vrow = vrow_off + i * 8;            // 0..127 (d index)
    const int vgc = vslot ^ (vrow & 7);
    vreg[i] = *(const uint4*)(vbase + (size_t)vrow * S_LEN + vgc * 8);
  }

  for (int kv0 = 0; kv0 < S_LEN; kv0 += 64) {
    // write staged regs -> LDS; layout identical to the global_load_lds dest:
    // lane*8 u16 == (lane>>4)*128 + (lane&15)*8 (K) == (lane>>3)*64 + (lane&7)*8 (V)
#pragma unroll
    for (int i = 0; i < 4; ++i) {
      *(uint4*)&Ks[(wave * 16 + i * 4) * 128 + lane * 8] = kreg[i];
      *(uint4*)&Vs[(wave * 32 + i * 8) * 64 + lane * 8] = vreg[i];
    }
    __syncthreads();

    // prefetch next tile into regs; arrives while we compute below
    if (kv0 + 64 < S_LEN) {
      const int kv1 = kv0 + 64;
#pragma unroll
      for (int i = 0; i < 4; ++i) {
        const int krow = krow_off + i * 4;
        const int kgc = kslot ^ (krow & 7);
        kreg[i] = *(const uint4*)(kbase + (size_t)(kv1 + krow) * LDQKV + kgc * 8);
        const int vrow = vrow_off + i * 8;
        const int vgc = vslot ^ (vrow & 7);
        vreg[i] = *(const uint4*)(vbase + (size_t)vrow * S_LEN + kv1 + vgc * 8);
      }
    }

    // S = Q K^T
    f32x4 sf[2][4] = {};
    __builtin_amdgcn_s_setprio(1);
#pragma unroll
    for (int nt = 0; nt < 4; ++nt) {
      bf16x8 bk[4];
#pragma unroll
      for (int kt = 0; kt < 4; ++kt)
        bk[kt] = *(const bf16x8*)&Ks[(nt * 16 + lane15) * 128 +
                                     (((kt * 4 + quad) ^ (lane15 & 7)) * 8)];
#pragma unroll
      for (int kt = 0; kt < 4; ++kt) {
        sf[0][nt] = __builtin_amdgcn_mfma_f32_16x16x32_bf16(aq[0][kt], bk[kt], sf[0][nt], 0, 0, 0);
        sf[1][nt] = __builtin_amdgcn_mfma_f32_16x16x32_bf16(aq[1][kt], bk[kt], sf[1][nt], 0, 0, 0);
      }
    }
    __builtin_amdgcn_s_setprio(0);

    // p = exp2(s*log2e/sqrt(HD)); per-lane l partials; P -> LDS (C->A layout)
#pragma unroll
    for (int mi = 0; mi < 2; ++mi)
#pragma unroll
      for (int nt = 0; nt < 4; ++nt)
#pragma unroll
        for (int r = 0; r < 4; ++r) {
          float pv = __builtin_amdgcn_exp2f(sf[mi][nt][r] * cexp);
          lsum[mi][r] += pv;
          Ps[wave][(mi * 16 + quad * 4 + r) * 72 + nt * 16 + lane15] = f2b(pv);
        }

    // O += P * V
    __builtin_amdgcn_s_setprio(1);
#pragma unroll
    for (int kt2 = 0; kt2 < 2; ++kt2) {
      bf16x8 ap0 = *(const bf16x8*)&Ps[wave][(lane15) * 72 + kt2 * 32 + quad * 8];
      bf16x8 ap1 = *(const bf16x8*)&Ps[wave][(16 + lane15) * 72 + kt2 * 32 + quad * 8];
#pragma unroll
      for (int nt2 = 0; nt2 < 8; ++nt2) {
        bf16x8 bv = *(const bf16x8*)&Vs[(nt2 * 16 + lane15) * 64 +
                                        (((kt2 * 4 + quad) ^ (lane15 & 7)) * 8)];
        o[0][nt2] = __builtin_amdgcn_mfma_f32_16x16x32_bf16(ap0, bv, o[0][nt2], 0, 0, 0);
        o[1][nt2] = __builtin_amdgcn_mfma_f32_16x16x32_bf16(ap1, bv, o[1][nt2], 0, 0, 0);
      }
    }
    __builtin_amdgcn_s_setprio(0);
    __syncthreads();
  }

#pragma unroll
  for (int mi = 0; mi < 2; ++mi)
#pragma unroll
    for (int r = 0; r < 4; ++r) {
      float l = lsum[mi][r];
      l += __shfl_xor(l, 1);
      l += __shfl_xor(l, 2);
      l += __shfl_xor(l, 4);
      l += __shfl_xor(l, 8);
      float inv = 1.0f / l;
      size_t row = q0 + mi * 16 + quad * 4 + r;
#pragma unroll
      for (int nt2 = 0; nt2 < 8; ++nt2)
        ctx[row * D_MODEL + h * HDIM + nt2 * 16 + lane15] = f2b(o[mi][nt2][r] * inv);
    }
}

// ---------------------------------------------------------------------------
extern "C" void kernel_launch(void* const* d_in, const int* in_sizes, int n_in,
                              void* d_out, int out_size, void* d_ws, size_t ws_size,
                              hipStream_t stream) {
  const float* hs    = (const float*)d_in[0];  // [2048][4096]
  const float* w_qkv = (const float*)d_in[1];  // [4096][12288]
  const float* wo    = (const float*)d_in[2];  // [4096][4096]
  float* out = (float*)d_out;

  // workspace layout (208 MB total)
  char* w = (char*)d_ws;
  u16* hsb   = (u16*)(w);                        // 16 MB  bf16 hidden [2048][4096]
  u16* wqkvT = (u16*)(w + (16u  << 20));         // 96 MB  bf16 w_qkv^T [12288][4096]
  u16* woT   = (u16*)(w + (112u << 20));         // 32 MB  bf16 wo^T [4096][4096]
  u16* qkvb  = (u16*)(w + (144u << 20));         // 48 MB  bf16 qkv [2048][12288]
  u16* vt    = (u16*)(w + (192u << 20));         // 16 MB  bf16 vt [32][128][2048]
  u16* ctx   = hsb;  // reuse: hsb consumed by gemm1 before attn writes ctx

  convert_f32_bf16<<<4096, 256, 0, stream>>>(hs, hsb);
  tconv<<<dim3(12288 / 64, 4096 / 64), 256, 0, stream>>>(w_qkv, wqkvT, 4096, 12288);
  tconv<<<dim3(4096 / 64, 4096 / 64), 256, 0, stream>>>(wo, woT, 4096, 4096);

  gemm_bt<u16><<<dim3(12288 / 128, 2048 / 128), 256, 0, stream>>>(
      hsb, wqkvT, qkvb, 2048, 12288, 4096);

  rope_kernel<<<(S_LEN * 2048) / 256, 256, 0, stream>>>(qkvb);
  transpose_v<<<dim3(32, 2, 32), 256, 0, stream>>>(qkvb, vt);
  attn_kernel<<<dim3(16, 32), 256, 0, stream>>>(qkvb, vt, ctx);

  gemm_bt<float><<<dim3(4096 / 128, 2048 / 128), 256, 0, stream>>>(
      ctx, woT, out, 2048, 4096, 4096);
}

// Round 2
// 884.778 us; speedup vs baseline: 1.0333x; 1.0333x over previous
//
#include <hip/hip_runtime.h>
#include <cstdint>

// Problem constants (B=1, S=2048, D=4096, H=32, HD=128)
#define S_LEN   2048
#define D_MODEL 4096
#define NHEAD   32
#define HDIM    128
#define LDQKV   12288  // 3*D

typedef __bf16 bf16x8 __attribute__((ext_vector_type(8)));
typedef float  f32x4  __attribute__((ext_vector_type(4)));
typedef unsigned short u16;
typedef unsigned int   u32;

union U16x8 { u16 u[8]; uint4 v; };

static __device__ __forceinline__ u16 f2b(float f) {
  u32 u = __builtin_bit_cast(u32, f);
  u += 0x7fffu + ((u >> 16) & 1u);   // RNE
  return (u16)(u >> 16);
}
static __device__ __forceinline__ float b2f(u16 h) {
  u32 u = ((u32)h) << 16;
  return __builtin_bit_cast(float, u);
}

// async global->LDS, 16B per lane; LDS dest is wave-uniform base + lane*16
#define GLOAD_LDS16(gp, lp)                                                   \
  __builtin_amdgcn_global_load_lds(                                           \
      (const __attribute__((address_space(1))) unsigned int*)(gp),            \
      (__attribute__((address_space(3))) unsigned int*)(lp), 16, 0, 0)

// ---------------- fp32 -> bf16 straight convert (hidden states) -------------
__global__ __launch_bounds__(256) void convert_f32_bf16(
    const float* __restrict__ in, u16* __restrict__ out) {
  size_t i = (size_t)blockIdx.x * 256 + threadIdx.x;   // 8 elems per thread
  const float4* p = (const float4*)in;
  float4 a = p[2 * i], b = p[2 * i + 1];
  U16x8 r;
  r.u[0] = f2b(a.x); r.u[1] = f2b(a.y); r.u[2] = f2b(a.z); r.u[3] = f2b(a.w);
  r.u[4] = f2b(b.x); r.u[5] = f2b(b.y); r.u[6] = f2b(b.z); r.u[7] = f2b(b.w);
  *(uint4*)(out + 8 * i) = r.v;
}

// ---------------- fp32 [R][C] -> bf16 [C][R] transpose+convert ---------------
__global__ __launch_bounds__(256) void tconv(
    const float* __restrict__ in, u16* __restrict__ out, int R, int C) {
  __shared__ u16 tile[64][65];
  const int r0 = blockIdx.y * 64, c0 = blockIdx.x * 64;
  const int tid = threadIdx.x;
  const int tr = tid >> 4, tc = (tid & 15) * 4;
#pragma unroll
  for (int p = 0; p < 4; ++p) {
    float4 v = *(const float4*)(in + (size_t)(r0 + p * 16 + tr) * C + c0 + tc);
    u16* t = &tile[p * 16 + tr][tc];
    t[0] = f2b(v.x); t[1] = f2b(v.y); t[2] = f2b(v.z); t[3] = f2b(v.w);
  }
  __syncthreads();
  const int oc = tid >> 3, os = (tid & 7) * 8;
#pragma unroll
  for (int p = 0; p < 2; ++p) {
    U16x8 u;
#pragma unroll
    for (int j = 0; j < 8; ++j) u.u[j] = tile[os + j][p * 32 + oc];
    *(uint4*)(out + (size_t)(c0 + p * 32 + oc) * R + r0 + os) = u.v;
  }
}

// ---------------- 256x256 deep-phase bf16 GEMM: C = A[M][K] * Bt[N][K]^T ----
// 512 thr = 8 waves (2M x 4N), per-wave 128x64 output (8x4 16x16 frags).
// BK=64, double-buffered LDS 128 KiB. Per K-tile: 4 phases of 16 MFMA
// {ds_read frags | barrier | setprio(1) 16xMFMA setprio(0) | barrier}.
// Full next-tile prefetch (8 global_load_lds) issued in phase 1 into the
// inactive buffer; single vmcnt(0)+barrier per tile => ~3 phases of slack.
// LDS chunk XOR swizzle identical to the verified 128^2 kernel (conflict-free).
template <typename OutT>
static __device__ __forceinline__ void gemm8p_body(
    const u16* __restrict__ A, const u16* __restrict__ Bt, OutT* __restrict__ C,
    int M, int N, int K) {
  __shared__ __align__(16) u16 As[2][256 * 64];
  __shared__ __align__(16) u16 Bs[2][256 * 64];
  const int tid = threadIdx.x;
  const int lane = tid & 63, wave = tid >> 6;
  const int lane15 = lane & 15, quad = lane >> 4;
  const int wm = (wave >> 2) * 128, wn = (wave & 3) * 64;

  // XCD-aware bijective swizzle (nwg % 8 == 0 for all our launches):
  // each XCD gets a contiguous run of tile-ids -> A row-panel hot in its L2.
  const int nbx = gridDim.x;
  const int nwg = nbx * gridDim.y;
  const int lin = (int)blockIdx.y * nbx + (int)blockIdx.x;
  const int xx = (lin & 7) * (nwg >> 3) + (lin >> 3);
  const size_t bm = (size_t)(xx / nbx) * 256, bn = (size_t)(xx % nbx) * 256;

  // staging map: thread -> (row = wave*8 + lane>>3 (+i*64), slot = lane&7),
  // global chunk = slot ^ (row&7)  (row&7 == lane>>3 here)
  const int srow = wave * 8 + (lane >> 3);
  const int scol = ((lane & 7) ^ (lane >> 3)) * 8;
  const u16* pA = A + (bm + srow) * (size_t)K + scol;
  const u16* pB = Bt + (bn + srow) * (size_t)K + scol;

  f32x4 acc[8][4] = {};
  bf16x8 af[4][2], bfr[2][2];

#define STAGE8(buf, k0)                                                       \
  {                                                                           \
    _Pragma("unroll") for (int i = 0; i < 4; ++i) {                           \
      GLOAD_LDS16(pA + (size_t)(i * 64) * K + (k0),                           \
                  &As[buf][(i * 64 + wave * 8) * 64]);                        \
      GLOAD_LDS16(pB + (size_t)(i * 64) * K + (k0),                           \
                  &Bs[buf][(i * 64 + wave * 8) * 64]);                        \
    }                                                                         \
  }
#define RDA8(buf, MB)                                                         \
  _Pragma("unroll") for (int m = 0; m < 4; ++m)                               \
      _Pragma("unroll") for (int kk = 0; kk < 2; ++kk)                        \
          af[m][kk] = *(const bf16x8*)&As[buf][(wm + (MB + m) * 16 + lane15) * 64 + \
                                              (((kk * 4 + quad) ^ (lane15 & 7)) * 8)];
#define RDB8(buf, NB)                                                         \
  _Pragma("unroll") for (int n = 0; n < 2; ++n)                               \
      _Pragma("unroll") for (int kk = 0; kk < 2; ++kk)                        \
          bfr[n][kk] = *(const bf16x8*)&Bs[buf][(wn + (NB + n) * 16 + lane15) * 64 + \
                                               (((kk * 4 + quad) ^ (lane15 & 7)) * 8)];
#define MM8(MB, NB)                                                           \
  __builtin_amdgcn_s_setprio(1);                                              \
  _Pragma("unroll") for (int m = 0; m < 4; ++m)                               \
      _Pragma("unroll") for (int n = 0; n < 2; ++n)                           \
          _Pragma("unroll") for (int kk = 0; kk < 2; ++kk)                    \
              acc[MB + m][NB + n] = __builtin_amdgcn_mfma_f32_16x16x32_bf16(  \
                  af[m][kk], bfr[n][kk], acc[MB + m][NB + n], 0, 0, 0);       \
  __builtin_amdgcn_s_setprio(0);
#define PHASE_PRE()                                                           \
  __builtin_amdgcn_s_barrier();                                               \
  __builtin_amdgcn_sched_barrier(0);
#define KITER(CUR, T)                                                         \
  {                                                                           \
    RDA8(CUR, 0);                                                             \
    RDB8(CUR, 0);                                                             \
    if ((T) + 1 < nt) STAGE8(CUR ^ 1, ((T) + 1) << 6);                        \
    PHASE_PRE(); MM8(0, 0); __builtin_amdgcn_s_barrier();                     \
    RDB8(CUR, 2);                                                             \
    PHASE_PRE(); MM8(0, 2); __builtin_amdgcn_s_barrier();                     \
    RDA8(CUR, 4);                                                             \
    PHASE_PRE(); MM8(4, 2); __builtin_amdgcn_s_barrier();                     \
    RDB8(CUR, 0);                                                             \
    PHASE_PRE(); MM8(4, 0);                                                   \
    asm volatile("s_waitcnt vmcnt(0)" ::: "memory");                          \
    __builtin_amdgcn_s_barrier();                                             \
    __builtin_amdgcn_sched_barrier(0);                                        \
  }

  const int nt = K >> 6;
  STAGE8(0, 0);
  asm volatile("s_waitcnt vmcnt(0)" ::: "memory");
  __builtin_amdgcn_s_barrier();

  for (int t = 0; t < nt; t += 2) {
    KITER(0, t);
    KITER(1, t + 1);
  }

#undef STAGE8
#undef RDA8
#undef RDB8
#undef MM8
#undef PHASE_PRE
#undef KITER

  // C/D layout: col = lane&15, row = quad*4 + r  [m89/m91 verified]
#pragma unroll
  for (int m = 0; m < 8; ++m)
#pragma unroll
    for (int r = 0; r < 4; ++r) {
      size_t row = bm + wm + m * 16 + quad * 4 + r;
#pragma unroll
      for (int n = 0; n < 4; ++n) {
        size_t col = bn + wn + n * 16 + lane15;
        float v = acc[m][n][r];
        if constexpr (sizeof(OutT) == 2) C[row * N + col] = (OutT)f2b(v);
        else                             C[row * N + col] = v;
      }
    }
}

__global__ __launch_bounds__(512, 2) void gemm8p_qkv(
    const u16* __restrict__ A, const u16* __restrict__ Bt, u16* __restrict__ C,
    int M, int N, int K) {
  gemm8p_body<u16>(A, Bt, C, M, N, K);
}

__global__ __launch_bounds__(512, 2) void gemm8p_out(
    const u16* __restrict__ A, const u16* __restrict__ Bt, float* __restrict__ C,
    int M, int N, int K) {
  gemm8p_body<float>(A, Bt, C, M, N, K);
}

// ---------------- RoPE in-place on Q,K of qkv [S][3D] -----------------------
__global__ __launch_bounds__(256) void rope_kernel(u16* __restrict__ qkv) {
  int idx = blockIdx.x * 256 + threadIdx.x;  // S*2048 pair-threads
  int s = idx >> 11;
  int p = idx & 2047;
  int h = p >> 6, j = p & 63;
  float freq = exp2f(-(float)j * 0.20762050593046015f);  // 10000^(-j/64)
  float ang = (float)s * freq;
  float sn = __sinf(ang), cs = __cosf(ang);
  size_t base = (size_t)s * LDQKV + h * HDIM + 2 * j;
  u32 q = *(const u32*)(qkv + base);
  float q0 = b2f((u16)(q & 0xffff)), q1 = b2f((u16)(q >> 16));
  u32 qo = (u32)f2b(q0 * cs - q1 * sn) | ((u32)f2b(q0 * sn + q1 * cs) << 16);
  *(u32*)(qkv + base) = qo;
  u32 k = *(const u32*)(qkv + base + D_MODEL);
  float k0 = b2f((u16)(k & 0xffff)), k1 = b2f((u16)(k >> 16));
  u32 ko = (u32)f2b(k0 * cs - k1 * sn) | ((u32)f2b(k0 * sn + k1 * cs) << 16);
  *(u32*)(qkv + base + D_MODEL) = ko;
}

// ---------------- V section of qkv -> vt[h][d][s] ---------------------------
__global__ __launch_bounds__(256) void transpose_v(
    const u16* __restrict__ qkv, u16* __restrict__ vt) {
  __shared__ u16 tile[64][65];
  const int s0 = blockIdx.x * 64, d0 = blockIdx.y * 64, h = blockIdx.z;
  const int tid = threadIdx.x;
  const int tr = tid >> 3, tc = (tid & 7) * 8;
#pragma unroll
  for (int p = 0; p < 2; ++p) {
    U16x8 u;
    u.v = *(const uint4*)(qkv + (size_t)(s0 + p * 32 + tr) * LDQKV + 2 * D_MODEL +
                          h * HDIM + d0 + tc);
    u16* t = &tile[p * 32 + tr][tc];
#pragma unroll
    for (int j = 0; j < 8; ++j) t[j] = u.u[j];
  }
  __syncthreads();
  const int dd = tid >> 3, ss = (tid & 7) * 8;
#pragma unroll
  for (int p = 0; p < 2; ++p) {
    U16x8 u;
#pragma unroll
    for (int j = 0; j < 8; ++j) u.u[j] = tile[ss + j][p * 32 + dd];
    *(uint4*)(vt + (size_t)h * HDIM * S_LEN + (size_t)(d0 + p * 32 + dd) * S_LEN +
              s0 + ss) = u.v;
  }
}

// ---------------- Flash attention (non-causal, fixed-max softmax) -----------
// Reverted to the round-0 version: global_load_lds staging (no register
// prefetch -- the T14 variant spilled: VGPR pressure -> 493 MB scratch writes).
__global__ __launch_bounds__(256, 2) void attn_kernel(
    const u16* __restrict__ qkv, const u16* __restrict__ vt, u16* __restrict__ ctx) {
  __shared__ __align__(16) u16 Ks[64 * 128];    // [kpos][d], XOR-swizzled 16B chunks
  __shared__ __align__(16) u16 Vs[128 * 64];    // [d][kpos], XOR-swizzled
  __shared__ __align__(16) u16 Ps[4][32 * 72];  // per-wave P, [q][kpos], stride 72
  const int h = blockIdx.y, qt = blockIdx.x;
  const int tid = threadIdx.x;
  const int lane = tid & 63, wave = tid >> 6;
  const int lane15 = lane & 15, quad = lane >> 4;
  const int q0 = qt * 128 + wave * 32;

  bf16x8 aq[2][4];
#pragma unroll
  for (int mi = 0; mi < 2; ++mi)
#pragma unroll
    for (int kt = 0; kt < 4; ++kt)
      aq[mi][kt] = *(const bf16x8*)(qkv + (size_t)(q0 + mi * 16 + lane15) * LDQKV +
                                    h * HDIM + kt * 32 + quad * 8);

  f32x4 o[2][8] = {};
  float lsum[2][4] = {};

  const int krow_off = wave * 16 + (lane >> 4);  // + i*4
  const int kslot = lane & 15;
  const int vrow_off = wave * 32 + (lane >> 3);  // + i*8
  const int vslot = lane & 7;
  const u16* kbase = qkv + D_MODEL + h * HDIM;
  const u16* vbase = vt + (size_t)h * HDIM * S_LEN;
  const float cexp = 0.12751879523243985f;  // log2(e)/sqrt(128)

  for (int kv0 = 0; kv0 < S_LEN; kv0 += 64) {
#pragma unroll
    for (int i = 0; i < 4; ++i) {
      const int krow = krow_off + i * 4;            // 0..63
      const int kgc = kslot ^ (krow & 7);
      GLOAD_LDS16(kbase + (size_t)(kv0 + krow) * LDQKV + kgc * 8,
                  &Ks[(wave * 16 + i * 4) * 128]);
      const int vrow = vrow_off + i * 8;            // 0..127 (d index)
      const int vgc = vslot ^ (vrow & 7);
      GLOAD_LDS16(vbase + (size_t)vrow * S_LEN + kv0 + vgc * 8,
                  &Vs[(wave * 32 + i * 8) * 64]);
    }
    __syncthreads();

    // S = Q K^T
    f32x4 sf[2][4] = {};
#pragma unroll
    for (int nt = 0; nt < 4; ++nt) {
      bf16x8 bk[4];
#pragma unroll
      for (int kt = 0; kt < 4; ++kt)
        bk[kt] = *(const bf16x8*)&Ks[(nt * 16 + lane15) * 128 +
                                     (((kt * 4 + quad) ^ (lane15 & 7)) * 8)];
#pragma unroll
      for (int kt = 0; kt < 4; ++kt) {
        sf[0][nt] = __builtin_amdgcn_mfma_f32_16x16x32_bf16(aq[0][kt], bk[kt], sf[0][nt], 0, 0, 0);
        sf[1][nt] = __builtin_amdgcn_mfma_f32_16x16x32_bf16(aq[1][kt], bk[kt], sf[1][nt], 0, 0, 0);
      }
    }

    // p = exp2(s*log2e/sqrt(HD)); per-lane l partials; P -> LDS (C->A layout)
#pragma unroll
    for (int mi = 0; mi < 2; ++mi)
#pragma unroll
      for (int nt = 0; nt < 4; ++nt)
#pragma unroll
        for (int r = 0; r < 4; ++r) {
          float pv = exp2f(sf[mi][nt][r] * cexp);
          lsum[mi][r] += pv;
          Ps[wave][(mi * 16 + quad * 4 + r) * 72 + nt * 16 + lane15] = f2b(pv);
        }

    // O += P * V
#pragma unroll
    for (int kt2 = 0; kt2 < 2; ++kt2) {
      bf16x8 ap0 = *(const bf16x8*)&Ps[wave][(lane15) * 72 + kt2 * 32 + quad * 8];
      bf16x8 ap1 = *(const bf16x8*)&Ps[wave][(16 + lane15) * 72 + kt2 * 32 + quad * 8];
#pragma unroll
      for (int nt2 = 0; nt2 < 8; ++nt2) {
        bf16x8 bv = *(const bf16x8*)&Vs[(nt2 * 16 + lane15) * 64 +
                                        (((kt2 * 4 + quad) ^ (lane15 & 7)) * 8)];
        o[0][nt2] = __builtin_amdgcn_mfma_f32_16x16x32_bf16(ap0, bv, o[0][nt2], 0, 0, 0);
        o[1][nt2] = __builtin_amdgcn_mfma_f32_16x16x32_bf16(ap1, bv, o[1][nt2], 0, 0, 0);
      }
    }
    __syncthreads();
  }

#pragma unroll
  for (int mi = 0; mi < 2; ++mi)
#pragma unroll
    for (int r = 0; r < 4; ++r) {
      float l = lsum[mi][r];
      l += __shfl_xor(l, 1);
      l += __shfl_xor(l, 2);
      l += __shfl_xor(l, 4);
      l += __shfl_xor(l, 8);
      float inv = 1.0f / l;
      size_t row = q0 + mi * 16 + quad * 4 + r;
#pragma unroll
      for (int nt2 = 0; nt2 < 8; ++nt2)
        ctx[row * D_MODEL + h * HDIM + nt2 * 16 + lane15] = f2b(o[mi][nt2][r] * inv);
    }
}

// ---------------------------------------------------------------------------
extern "C" void kernel_launch(void* const* d_in, const int* in_sizes, int n_in,
                              void* d_out, int out_size, void* d_ws, size_t ws_size,
                              hipStream_t stream) {
  const float* hs    = (const float*)d_in[0];  // [2048][4096]
  const float* w_qkv = (const float*)d_in[1];  // [4096][12288]
  const float* wo    = (const float*)d_in[2];  // [4096][4096]
  float* out = (float*)d_out;

  // workspace layout (208 MB total)
  char* w = (char*)d_ws;
  u16* hsb   = (u16*)(w);                        // 16 MB  bf16 hidden [2048][4096]
  u16* wqkvT = (u16*)(w + (16u  << 20));         // 96 MB  bf16 w_qkv^T [12288][4096]
  u16* woT   = (u16*)(w + (112u << 20));         // 32 MB  bf16 wo^T [4096][4096]
  u16* qkvb  = (u16*)(w + (144u << 20));         // 48 MB  bf16 qkv [2048][12288]
  u16* vt    = (u16*)(w + (192u << 20));         // 16 MB  bf16 vt [32][128][2048]
  u16* ctx   = hsb;  // reuse: hsb consumed by gemm1 before attn writes ctx

  convert_f32_bf16<<<4096, 256, 0, stream>>>(hs, hsb);
  tconv<<<dim3(12288 / 64, 4096 / 64), 256, 0, stream>>>(w_qkv, wqkvT, 4096, 12288);
  tconv<<<dim3(4096 / 64, 4096 / 64), 256, 0, stream>>>(wo, woT, 4096, 4096);

  gemm8p_qkv<<<dim3(12288 / 256, 2048 / 256), 512, 0, stream>>>(
      hsb, wqkvT, qkvb, 2048, 12288, 4096);

  rope_kernel<<<(S_LEN * 2048) / 256, 256, 0, stream>>>(qkvb);
  transpose_v<<<dim3(32, 2, 32), 256, 0, stream>>>(qkvb, vt);
  attn_kernel<<<dim3(16, 32), 256, 0, stream>>>(qkvb, vt, ctx);

  gemm8p_out<<<dim3(4096 / 256, 2048 / 256), 512, 0, stream>>>(
      ctx, woT, out, 2048, 4096, 4096);
}

// Round 3
// 852.535 us; speedup vs baseline: 1.0724x; 1.0378x over previous
//
#include <hip/hip_runtime.h>
#include <cstdint>

// Problem constants (B=1, S=2048, D=4096, H=32, HD=128)
#define S_LEN   2048
#define D_MODEL 4096
#define NHEAD   32
#define HDIM    128
#define LDQKV   12288  // 3*D

typedef __bf16 bf16x8 __attribute__((ext_vector_type(8)));
typedef float  f32x4  __attribute__((ext_vector_type(4)));
typedef unsigned short u16;
typedef unsigned int   u32;

union U16x8 { u16 u[8]; uint4 v; };

static __device__ __forceinline__ u16 f2b(float f) {
  u32 u = __builtin_bit_cast(u32, f);
  u += 0x7fffu + ((u >> 16) & 1u);   // RNE
  return (u16)(u >> 16);
}
static __device__ __forceinline__ float b2f(u16 h) {
  u32 u = ((u32)h) << 16;
  return __builtin_bit_cast(float, u);
}

// async global->LDS, 16B per lane; LDS dest is wave-uniform base + lane*16
#define GLOAD_LDS16(gp, lp)                                                   \
  __builtin_amdgcn_global_load_lds(                                           \
      (const __attribute__((address_space(1))) unsigned int*)(gp),            \
      (__attribute__((address_space(3))) unsigned int*)(lp), 16, 0, 0)

// ---------------- fp32 -> bf16 straight convert (hidden states) -------------
__global__ __launch_bounds__(256) void convert_f32_bf16(
    const float* __restrict__ in, u16* __restrict__ out) {
  size_t i = (size_t)blockIdx.x * 256 + threadIdx.x;   // 8 elems per thread
  const float4* p = (const float4*)in;
  float4 a = p[2 * i], b = p[2 * i + 1];
  U16x8 r;
  r.u[0] = f2b(a.x); r.u[1] = f2b(a.y); r.u[2] = f2b(a.z); r.u[3] = f2b(a.w);
  r.u[4] = f2b(b.x); r.u[5] = f2b(b.y); r.u[6] = f2b(b.z); r.u[7] = f2b(b.w);
  *(uint4*)(out + 8 * i) = r.v;
}

// ---------------- fp32 [R][C] -> bf16 [C][R] transpose+convert ---------------
__global__ __launch_bounds__(256) void tconv(
    const float* __restrict__ in, u16* __restrict__ out, int R, int C) {
  __shared__ u16 tile[64][65];
  const int r0 = blockIdx.y * 64, c0 = blockIdx.x * 64;
  const int tid = threadIdx.x;
  const int tr = tid >> 4, tc = (tid & 15) * 4;
#pragma unroll
  for (int p = 0; p < 4; ++p) {
    float4 v = *(const float4*)(in + (size_t)(r0 + p * 16 + tr) * C + c0 + tc);
    u16* t = &tile[p * 16 + tr][tc];
    t[0] = f2b(v.x); t[1] = f2b(v.y); t[2] = f2b(v.z); t[3] = f2b(v.w);
  }
  __syncthreads();
  const int oc = tid >> 3, os = (tid & 7) * 8;
#pragma unroll
  for (int p = 0; p < 2; ++p) {
    U16x8 u;
#pragma unroll
    for (int j = 0; j < 8; ++j) u.u[j] = tile[os + j][p * 32 + oc];
    *(uint4*)(out + (size_t)(c0 + p * 32 + oc) * R + r0 + os) = u.v;
  }
}

// ---------------- 256x256 counted-vmcnt bf16 GEMM: C = A * Bt^T -------------
// 512 thr = 8 waves (2M x 4N), per-wave 128x64 output (8x4 16x16 frags).
// BK=64, double-buffered 128 KiB LDS split in half-tiles.
// PER-WAVE-RELATIVE staging: each wave stages slices of exactly the data it
// consumes, in consumption order:
//   s1 = own-B rows 0-31, s2 = own-A rows 0-63, s3 = own-B 32-63, s4 = own-A 64-127
// Slot j of tile t+1 issued at phase j of tile t (2 loads each). Phase needs:
//   P1 <- {t.s1,t.s2}, P2 <- {t.s3}, P3 <- {t.s4}, P4 <- (s1 re-read).
// => uniform s_waitcnt vmcnt(4)+barrier at P1/P2/P3, nothing at P4; never a
// full drain in the main loop (last tile peels to one vmcnt(0)).
// Per-wave vmcnt + barrier gives collective prefix completion because all
// waves' load streams are symmetric. Chunk XOR swizzle as in the verified
// 128^2 kernel (bank-conflict counter measured 0).
#define WAITV4() asm volatile("s_waitcnt vmcnt(4)" ::: "memory")
#define WAITV0() asm volatile("s_waitcnt vmcnt(0)" ::: "memory")
#define BAR()                                                                 \
  __builtin_amdgcn_sched_barrier(0);                                          \
  asm volatile("s_barrier" ::: "memory");                                     \
  __builtin_amdgcn_sched_barrier(0)

template <typename OutT>
static __device__ __forceinline__ void gemm256_body(
    const u16* __restrict__ A, const u16* __restrict__ Bt, OutT* __restrict__ C,
    int M, int N, int K) {
  __shared__ __align__(16) u16 As[2 * 16384];  // [buf][half][128*64]
  __shared__ __align__(16) u16 Bs[2 * 16384];
  const int tid = threadIdx.x;
  const int lane = tid & 63, wave = tid >> 6;
  const int lane15 = lane & 15, quad = lane >> 4;
  const int g  = wave >> 2;          // A-group = own A-half (0: rows 0-127)
  const int wg = wave & 3;           // wave within A-group
  const int hB = (wave & 3) >> 1;    // own B-half
  const int bb = (wave & 1) * 64;    // own B band base within half
  const int wm = g * 128, wn = (wave & 3) * 64;
  const int l8 = lane >> 3;
  const int gcS = ((lane & 7) ^ l8) * 8;   // staged chunk offset (u16)

  // XCD-aware bijective swizzle (nwg % 8 == 0 for all our launches)
  const int nbx = gridDim.x;
  const int nwg = nbx * gridDim.y;
  const int lin = (int)blockIdx.y * nbx + (int)blockIdx.x;
  const int xx = (lin & 7) * (nwg >> 3) + (lin >> 3);
  const size_t bm = (size_t)(xx / nbx) * 256, bn = (size_t)(xx % nbx) * 256;

  f32x4 acc[8][4] = {};
  bf16x8 af[4][2], bfr[2][2];

  // ---- staging macros: round r of own-A (32 rows) / own-B (16 rows) ----
#define STG_A(buf, k0, r)                                                     \
  GLOAD_LDS16(A + (size_t)(bm + g * 128 + (r) * 32 + wg * 8 + l8) * K + (k0) + gcS, \
              &As[(buf) * 16384 + g * 8192 + ((r) * 32 + wg * 8) * 64])
#define STG_B(buf, k0, r)                                                     \
  GLOAD_LDS16(Bt + (size_t)(bn + wn + (r) * 16 + g * 8 + l8) * K + (k0) + gcS, \
              &Bs[(buf) * 16384 + hB * 8192 + (bb + (r) * 16 + g * 8) * 64])
#define RD_AF(buf, MB)                                                        \
  _Pragma("unroll") for (int m = 0; m < 4; ++m)                               \
      _Pragma("unroll") for (int kk = 0; kk < 2; ++kk)                        \
          af[m][kk] = *(const bf16x8*)&As[(buf) * 16384 + g * 8192 +          \
              (((MB) + m) * 16 + lane15) * 64 +                               \
              (((kk * 4 + quad) ^ (lane15 & 7)) * 8)];
#define RD_BF(buf, NB)                                                        \
  _Pragma("unroll") for (int n = 0; n < 2; ++n)                               \
      _Pragma("unroll") for (int kk = 0; kk < 2; ++kk)                        \
          bfr[n][kk] = *(const bf16x8*)&Bs[(buf) * 16384 + hB * 8192 +        \
              (bb + ((NB) + n) * 16 + lane15) * 64 +                          \
              (((kk * 4 + quad) ^ (lane15 & 7)) * 8)];
#define MFMA16(MB, NB)                                                        \
  __builtin_amdgcn_s_setprio(1);                                              \
  _Pragma("unroll") for (int m = 0; m < 4; ++m)                               \
      _Pragma("unroll") for (int n = 0; n < 2; ++n)                           \
          _Pragma("unroll") for (int kk = 0; kk < 2; ++kk)                    \
              acc[(MB) + m][(NB) + n] = __builtin_amdgcn_mfma_f32_16x16x32_bf16( \
                  af[m][kk], bfr[n][kk], acc[(MB) + m][(NB) + n], 0, 0, 0);   \
  __builtin_amdgcn_s_setprio(0);

  const int nt = K >> 6;
  // prologue: stage tile 0 in slot order s1,s2,s3,s4
  STG_B(0, 0, 0); STG_B(0, 0, 1);
  STG_A(0, 0, 0); STG_A(0, 0, 1);
  STG_B(0, 0, 2); STG_B(0, 0, 3);
  STG_A(0, 0, 2); STG_A(0, 0, 3);

  for (int t = 0; t < nt; ++t) {
    const int cur = t & 1, nxt = cur ^ 1;
    const bool pf = (t + 1 < nt);
    const int kn = (t + 1) << 6;
    // P1: needs t.s1,t.s2 (4 younger loads in flight) ------------------------
    if (pf) { WAITV4(); } else { WAITV0(); }
    BAR();
    RD_AF(cur, 0); RD_BF(cur, 0);
    if (pf) { STG_B(nxt, kn, 0); STG_B(nxt, kn, 1); }   // t+1.s1
    MFMA16(0, 0);
    // P2: needs t.s3 ---------------------------------------------------------
    if (pf) { WAITV4(); BAR(); }
    RD_BF(cur, 2);
    if (pf) { STG_A(nxt, kn, 0); STG_A(nxt, kn, 1); }   // t+1.s2
    MFMA16(0, 2);
    // P3: needs t.s4 ---------------------------------------------------------
    if (pf) { WAITV4(); BAR(); }
    RD_AF(cur, 4);
    if (pf) { STG_B(nxt, kn, 2); STG_B(nxt, kn, 3); }   // t+1.s3
    MFMA16(4, 2);
    // P4: no new data --------------------------------------------------------
    RD_BF(cur, 0);
    if (pf) { STG_A(nxt, kn, 2); STG_A(nxt, kn, 3); }   // t+1.s4
    MFMA16(4, 0);
  }

#undef STG_A
#undef STG_B
#undef RD_AF
#undef RD_BF
#undef MFMA16

  // C/D layout: col = lane&15, row = quad*4 + r  [m89/m91 verified]
#pragma unroll
  for (int m = 0; m < 8; ++m)
#pragma unroll
    for (int r = 0; r < 4; ++r) {
      size_t row = bm + wm + m * 16 + quad * 4 + r;
#pragma unroll
      for (int n = 0; n < 4; ++n) {
        size_t col = bn + wn + n * 16 + lane15;
        float v = acc[m][n][r];
        if constexpr (sizeof(OutT) == 2) C[row * N + col] = (OutT)f2b(v);
        else                             C[row * N + col] = v;
      }
    }
}

__global__ __launch_bounds__(512, 2) void gemm256_qkv(
    const u16* __restrict__ A, const u16* __restrict__ Bt, u16* __restrict__ C,
    int M, int N, int K) {
  gemm256_body<u16>(A, Bt, C, M, N, K);
}

__global__ __launch_bounds__(512, 2) void gemm256_out(
    const u16* __restrict__ A, const u16* __restrict__ Bt, float* __restrict__ C,
    int M, int N, int K) {
  gemm256_body<float>(A, Bt, C, M, N, K);
}

// ---------------- RoPE in-place on Q,K of qkv [S][3D] -----------------------
__global__ __launch_bounds__(256) void rope_kernel(u16* __restrict__ qkv) {
  int idx = blockIdx.x * 256 + threadIdx.x;  // S*2048 pair-threads
  int s = idx >> 11;
  int p = idx & 2047;
  int h = p >> 6, j = p & 63;
  float freq = exp2f(-(float)j * 0.20762050593046015f);  // 10000^(-j/64)
  float ang = (float)s * freq;
  float sn = __sinf(ang), cs = __cosf(ang);
  size_t base = (size_t)s * LDQKV + h * HDIM + 2 * j;
  u32 q = *(const u32*)(qkv + base);
  float q0 = b2f((u16)(q & 0xffff)), q1 = b2f((u16)(q >> 16));
  u32 qo = (u32)f2b(q0 * cs - q1 * sn) | ((u32)f2b(q0 * sn + q1 * cs) << 16);
  *(u32*)(qkv + base) = qo;
  u32 k = *(const u32*)(qkv + base + D_MODEL);
  float k0 = b2f((u16)(k & 0xffff)), k1 = b2f((u16)(k >> 16));
  u32 ko = (u32)f2b(k0 * cs - k1 * sn) | ((u32)f2b(k0 * sn + k1 * cs) << 16);
  *(u32*)(qkv + base + D_MODEL) = ko;
}

// ---------------- V section of qkv -> vt[h][d][s] ---------------------------
__global__ __launch_bounds__(256) void transpose_v(
    const u16* __restrict__ qkv, u16* __restrict__ vt) {
  __shared__ u16 tile[64][65];
  const int s0 = blockIdx.x * 64, d0 = blockIdx.y * 64, h = blockIdx.z;
  const int tid = threadIdx.x;
  const int tr = tid >> 3, tc = (tid & 7) * 8;
#pragma unroll
  for (int p = 0; p < 2; ++p) {
    U16x8 u;
    u.v = *(const uint4*)(qkv + (size_t)(s0 + p * 32 + tr) * LDQKV + 2 * D_MODEL +
                          h * HDIM + d0 + tc);
    u16* t = &tile[p * 32 + tr][tc];
#pragma unroll
    for (int j = 0; j < 8; ++j) t[j] = u.u[j];
  }
  __syncthreads();
  const int dd = tid >> 3, ss = (tid & 7) * 8;
#pragma unroll
  for (int p = 0; p < 2; ++p) {
    U16x8 u;
#pragma unroll
    for (int j = 0; j < 8; ++j) u.u[j] = tile[ss + j][p * 32 + dd];
    *(uint4*)(vt + (size_t)h * HDIM * S_LEN + (size_t)(d0 + p * 32 + dd) * S_LEN +
              s0 + ss) = u.v;
  }
}

// ---------------- Flash attention (non-causal, fixed-max softmax) -----------
// Round-0 proven version: global_load_lds staging, ~107 us.
__global__ __launch_bounds__(256, 2) void attn_kernel(
    const u16* __restrict__ qkv, const u16* __restrict__ vt, u16* __restrict__ ctx) {
  __shared__ __align__(16) u16 Ks[64 * 128];    // [kpos][d], XOR-swizzled 16B chunks
  __shared__ __align__(16) u16 Vs[128 * 64];    // [d][kpos], XOR-swizzled
  __shared__ __align__(16) u16 Ps[4][32 * 72];  // per-wave P, [q][kpos], stride 72
  const int h = blockIdx.y, qt = blockIdx.x;
  const int tid = threadIdx.x;
  const int lane = tid & 63, wave = tid >> 6;
  const int lane15 = lane & 15, quad = lane >> 4;
  const int q0 = qt * 128 + wave * 32;

  bf16x8 aq[2][4];
#pragma unroll
  for (int mi = 0; mi < 2; ++mi)
#pragma unroll
    for (int kt = 0; kt < 4; ++kt)
      aq[mi][kt] = *(const bf16x8*)(qkv + (size_t)(q0 + mi * 16 + lane15) * LDQKV +
                                    h * HDIM + kt * 32 + quad * 8);

  f32x4 o[2][8] = {};
  float lsum[2][4] = {};

  const int krow_off = wave * 16 + (lane >> 4);  // + i*4
  const int kslot = lane & 15;
  const int vrow_off = wave * 32 + (lane >> 3);  // + i*8
  const int vslot = lane & 7;
  const u16* kbase = qkv + D_MODEL + h * HDIM;
  const u16* vbase = vt + (size_t)h * HDIM * S_LEN;
  const float cexp = 0.12751879523243985f;  // log2(e)/sqrt(128)

  for (int kv0 = 0; kv0 < S_LEN; kv0 += 64) {
#pragma unroll
    for (int i = 0; i < 4; ++i) {
      const int krow = krow_off + i * 4;            // 0..63
      const int kgc = kslot ^ (krow & 7);
      GLOAD_LDS16(kbase + (size_t)(kv0 + krow) * LDQKV + kgc * 8,
                  &Ks[(wave * 16 + i * 4) * 128]);
      const int vrow = vrow_off + i * 8;            // 0..127 (d index)
      const int vgc = vslot ^ (vrow & 7);
      GLOAD_LDS16(vbase + (size_t)vrow * S_LEN + kv0 + vgc * 8,
                  &Vs[(wave * 32 + i * 8) * 64]);
    }
    __syncthreads();

    // S = Q K^T
    f32x4 sf[2][4] = {};
#pragma unroll
    for (int nt = 0; nt < 4; ++nt) {
      bf16x8 bk[4];
#pragma unroll
      for (int kt = 0; kt < 4; ++kt)
        bk[kt] = *(const bf16x8*)&Ks[(nt * 16 + lane15) * 128 +
                                     (((kt * 4 + quad) ^ (lane15 & 7)) * 8)];
#pragma unroll
      for (int kt = 0; kt < 4; ++kt) {
        sf[0][nt] = __builtin_amdgcn_mfma_f32_16x16x32_bf16(aq[0][kt], bk[kt], sf[0][nt], 0, 0, 0);
        sf[1][nt] = __builtin_amdgcn_mfma_f32_16x16x32_bf16(aq[1][kt], bk[kt], sf[1][nt], 0, 0, 0);
      }
    }

    // p = exp2(s*log2e/sqrt(HD)); per-lane l partials; P -> LDS (C->A layout)
#pragma unroll
    for (int mi = 0; mi < 2; ++mi)
#pragma unroll
      for (int nt = 0; nt < 4; ++nt)
#pragma unroll
        for (int r = 0; r < 4; ++r) {
          float pv = exp2f(sf[mi][nt][r] * cexp);
          lsum[mi][r] += pv;
          Ps[wave][(mi * 16 + quad * 4 + r) * 72 + nt * 16 + lane15] = f2b(pv);
        }

    // O += P * V
#pragma unroll
    for (int kt2 = 0; kt2 < 2; ++kt2) {
      bf16x8 ap0 = *(const bf16x8*)&Ps[wave][(lane15) * 72 + kt2 * 32 + quad * 8];
      bf16x8 ap1 = *(const bf16x8*)&Ps[wave][(16 + lane15) * 72 + kt2 * 32 + quad * 8];
#pragma unroll
      for (int nt2 = 0; nt2 < 8; ++nt2) {
        bf16x8 bv = *(const bf16x8*)&Vs[(nt2 * 16 + lane15) * 64 +
                                        (((kt2 * 4 + quad) ^ (lane15 & 7)) * 8)];
        o[0][nt2] = __builtin_amdgcn_mfma_f32_16x16x32_bf16(ap0, bv, o[0][nt2], 0, 0, 0);
        o[1][nt2] = __builtin_amdgcn_mfma_f32_16x16x32_bf16(ap1, bv, o[1][nt2], 0, 0, 0);
      }
    }
    __syncthreads();
  }

#pragma unroll
  for (int mi = 0; mi < 2; ++mi)
#pragma unroll
    for (int r = 0; r < 4; ++r) {
      float l = lsum[mi][r];
      l += __shfl_xor(l, 1);
      l += __shfl_xor(l, 2);
      l += __shfl_xor(l, 4);
      l += __shfl_xor(l, 8);
      float inv = 1.0f / l;
      size_t row = q0 + mi * 16 + quad * 4 + r;
#pragma unroll
      for (int nt2 = 0; nt2 < 8; ++nt2)
        ctx[row * D_MODEL + h * HDIM + nt2 * 16 + lane15] = f2b(o[mi][nt2][r] * inv);
    }
}

// ---------------------------------------------------------------------------
extern "C" void kernel_launch(void* const* d_in, const int* in_sizes, int n_in,
                              void* d_out, int out_size, void* d_ws, size_t ws_size,
                              hipStream_t stream) {
  const float* hs    = (const float*)d_in[0];  // [2048][4096]
  const float* w_qkv = (const float*)d_in[1];  // [4096][12288]
  const float* wo    = (const float*)d_in[2];  // [4096][4096]
  float* out = (float*)d_out;

  // workspace layout (208 MB total)
  char* w = (char*)d_ws;
  u16* hsb   = (u16*)(w);                        // 16 MB  bf16 hidden [2048][4096]
  u16* wqkvT = (u16*)(w + (16u  << 20));         // 96 MB  bf16 w_qkv^T [12288][4096]
  u16* woT   = (u16*)(w + (112u << 20));         // 32 MB  bf16 wo^T [4096][4096]
  u16* qkvb  = (u16*)(w + (144u << 20));         // 48 MB  bf16 qkv [2048][12288]
  u16* vt    = (u16*)(w + (192u << 20));         // 16 MB  bf16 vt [32][128][2048]
  u16* ctx   = hsb;  // reuse: hsb consumed by gemm1 before attn writes ctx

  convert_f32_bf16<<<4096, 256, 0, stream>>>(hs, hsb);
  tconv<<<dim3(12288 / 64, 4096 / 64), 256, 0, stream>>>(w_qkv, wqkvT, 4096, 12288);
  tconv<<<dim3(4096 / 64, 4096 / 64), 256, 0, stream>>>(wo, woT, 4096, 4096);

  gemm256_qkv<<<dim3(12288 / 256, 2048 / 256), 512, 0, stream>>>(
      hsb, wqkvT, qkvb, 2048, 12288, 4096);

  rope_kernel<<<(S_LEN * 2048) / 256, 256, 0, stream>>>(qkvb);
  transpose_v<<<dim3(32, 2, 32), 256, 0, stream>>>(qkvb, vt);
  attn_kernel<<<dim3(16, 32), 256, 0, stream>>>(qkvb, vt, ctx);

  gemm256_out<<<dim3(4096 / 256, 2048 / 256), 512, 0, stream>>>(
      ctx, woT, out, 2048, 4096, 4096);
}

// Round 4
// 825.325 us; speedup vs baseline: 1.1078x; 1.0330x over previous
//
#include <hip/hip_runtime.h>
#include <cstdint>

// Problem constants (B=1, S=2048, D=4096, H=32, HD=128)
#define S_LEN   2048
#define D_MODEL 4096
#define NHEAD   32
#define HDIM    128
#define LDQKV   12288  // 3*D

typedef __bf16 bf16x8 __attribute__((ext_vector_type(8)));
typedef float  f32x4  __attribute__((ext_vector_type(4)));
typedef unsigned short u16;
typedef unsigned int   u32;

union U16x8 { u16 u[8]; uint4 v; };

static __device__ __forceinline__ u16 f2b(float f) {
  u32 u = __builtin_bit_cast(u32, f);
  u += 0x7fffu + ((u >> 16) & 1u);   // RNE
  return (u16)(u >> 16);
}
static __device__ __forceinline__ float b2f(u16 h) {
  u32 u = ((u32)h) << 16;
  return __builtin_bit_cast(float, u);
}

// async global->LDS, 16B per lane; LDS dest is wave-uniform base + lane*16
#define GLOAD_LDS16(gp, lp)                                                   \
  __builtin_amdgcn_global_load_lds(                                           \
      (const __attribute__((address_space(1))) unsigned int*)(gp),            \
      (__attribute__((address_space(3))) unsigned int*)(lp), 16, 0, 0)

// ---------------- fp32 -> bf16 straight convert (hidden states) -------------
__global__ __launch_bounds__(256) void convert_f32_bf16(
    const float* __restrict__ in, u16* __restrict__ out) {
  size_t i = (size_t)blockIdx.x * 256 + threadIdx.x;   // 8 elems per thread
  const float4* p = (const float4*)in;
  float4 a = p[2 * i], b = p[2 * i + 1];
  U16x8 r;
  r.u[0] = f2b(a.x); r.u[1] = f2b(a.y); r.u[2] = f2b(a.z); r.u[3] = f2b(a.w);
  r.u[4] = f2b(b.x); r.u[5] = f2b(b.y); r.u[6] = f2b(b.z); r.u[7] = f2b(b.w);
  *(uint4*)(out + 8 * i) = r.v;
}

// ---------------- fp32 [R][C] -> bf16 [C][R] transpose+convert ---------------
__global__ __launch_bounds__(256) void tconv(
    const float* __restrict__ in, u16* __restrict__ out, int R, int C) {
  __shared__ u16 tile[64][65];
  const int r0 = blockIdx.y * 64, c0 = blockIdx.x * 64;
  const int tid = threadIdx.x;
  const int tr = tid >> 4, tc = (tid & 15) * 4;
#pragma unroll
  for (int p = 0; p < 4; ++p) {
    float4 v = *(const float4*)(in + (size_t)(r0 + p * 16 + tr) * C + c0 + tc);
    u16* t = &tile[p * 16 + tr][tc];
    t[0] = f2b(v.x); t[1] = f2b(v.y); t[2] = f2b(v.z); t[3] = f2b(v.w);
  }
  __syncthreads();
  const int oc = tid >> 3, os = (tid & 7) * 8;
#pragma unroll
  for (int p = 0; p < 2; ++p) {
    U16x8 u;
#pragma unroll
    for (int j = 0; j < 8; ++j) u.u[j] = tile[os + j][p * 32 + oc];
    *(uint4*)(out + (size_t)(c0 + p * 32 + oc) * R + r0 + os) = u.v;
  }
}

// ---------------- 256x256 v3 bf16 GEMM: C = A[M][K] * Bt[N][K]^T -------------
// 512 thr = 8 waves (2M x 4N), per-wave 128x64 output, BK=64, 128 KiB dbuf LDS.
// v3 phase = [ds_read regs][stage next-tile slot][vmcnt(N)][BAR][16 MFMA][BAR]
// -- reads at phase TOP (overlap other waves' previous MFMA, m201 style).
// Stage plan per tile t (for t+1): P1: s1(ownB r0-31)+s2(ownA r0-63) [4 ld],
// P2: s3(ownB r32-63) [2], P3: s4(ownA r64-127) [2], P4: none.
// FIFO-verified waits: P1 vmcnt(6) retires s3(t); P2 vmcnt(6) retires s4(t);
// P4 vmcnt(4) retires s1s2(t+1). 3-phase slack everywhere; vmcnt(0) only in
// the peeled last tile. P4 reuses P1's B-frags from registers (b0s).
#define SB0() __builtin_amdgcn_sched_barrier(0)
#define SBAR() asm volatile("s_barrier" ::: "memory")
#define VMW6() asm volatile("s_waitcnt vmcnt(6)" ::: "memory")
#define VMW4() asm volatile("s_waitcnt vmcnt(4)" ::: "memory")
#define VMW2() asm volatile("s_waitcnt vmcnt(2)" ::: "memory")
#define VMW0() asm volatile("s_waitcnt vmcnt(0)" ::: "memory")
#define BARF() SB0(); SBAR(); SB0()

__global__ __launch_bounds__(512, 2) void gemm256v3_qkv(
    const u16* __restrict__ A, const u16* __restrict__ Bt, u16* __restrict__ C,
    int M, int NS, int K) {  // NS = C row stride (12288); this launch: 24x8 tiles
  __shared__ __align__(16) u16 As[2 * 16384];  // [buf][g-half 128x64]
  __shared__ __align__(16) u16 Bs[2 * 16384];  // [buf][hB-half 128x64]
  const int tid = threadIdx.x;
  const int lane = tid & 63, wave = tid >> 6;
  const int lane15 = lane & 15, quad = lane >> 4;
  const int g  = wave >> 2;          // own A-half
  const int wg = wave & 3;
  const int hB = (wave & 3) >> 1;    // own B-half
  const int bb = (wave & 1) * 64;    // own B band base within half
  const int wm = g * 128, wn = (wave & 3) * 64;
  const int l8 = lane >> 3;
  const int gcS = ((lane & 7) ^ l8) * 8;   // staged chunk offset (u16)

  // XCD-aware bijective swizzle (nwg = 192, %8==0)
  const int nbx = gridDim.x;
  const int nwg = nbx * gridDim.y;
  const int lin = (int)blockIdx.y * nbx + (int)blockIdx.x;
  const int xx = (lin & 7) * (nwg >> 3) + (lin >> 3);
  const size_t bm = (size_t)(xx / nbx) * 256, bn = (size_t)(xx % nbx) * 256;

  f32x4 acc[8][4] = {};
  bf16x8 af[4][2], bfr[2][2], b0s[2][2];

#define STG_A(buf, k0, r)                                                     \
  GLOAD_LDS16(A + (size_t)(bm + g * 128 + (r) * 32 + wg * 8 + l8) * K + (k0) + gcS, \
              &As[(buf) * 16384 + g * 8192 + ((r) * 32 + wg * 8) * 64])
#define STG_B(buf, k0, r)                                                     \
  GLOAD_LDS16(Bt + (size_t)(bn + wn + (r) * 16 + g * 8 + l8) * K + (k0) + gcS, \
              &Bs[(buf) * 16384 + hB * 8192 + (bb + (r) * 16 + g * 8) * 64])
#define RD_AF(buf, MB)                                                        \
  _Pragma("unroll") for (int m = 0; m < 4; ++m)                               \
      _Pragma("unroll") for (int kk = 0; kk < 2; ++kk)                        \
          af[m][kk] = *(const bf16x8*)&As[(buf) * 16384 + g * 8192 +          \
              (((MB) + m) * 16 + lane15) * 64 +                               \
              (((kk * 4 + quad) ^ (lane15 & 7)) * 8)];
#define RD_BF(buf, NB, DST)                                                   \
  _Pragma("unroll") for (int n = 0; n < 2; ++n)                               \
      _Pragma("unroll") for (int kk = 0; kk < 2; ++kk)                        \
          DST[n][kk] = *(const bf16x8*)&Bs[(buf) * 16384 + hB * 8192 +        \
              (bb + ((NB) + n) * 16 + lane15) * 64 +                          \
              (((kk * 4 + quad) ^ (lane15 & 7)) * 8)];
#define MFMA16(MB, NB, BOP)                                                   \
  __builtin_amdgcn_s_setprio(1);                                              \
  _Pragma("unroll") for (int m = 0; m < 4; ++m)                               \
      _Pragma("unroll") for (int n = 0; n < 2; ++n)                           \
          _Pragma("unroll") for (int kk = 0; kk < 2; ++kk)                    \
              acc[(MB) + m][(NB) + n] = __builtin_amdgcn_mfma_f32_16x16x32_bf16( \
                  af[m][kk], BOP[n][kk], acc[(MB) + m][(NB) + n], 0, 0, 0);   \
  __builtin_amdgcn_s_setprio(0);

  const int nt = K >> 6;
  // prologue: stage tile 0 in slot order s1,s2,s3,s4 (8 loads)
  STG_B(0, 0, 0); STG_B(0, 0, 1);   // s1
  STG_A(0, 0, 0); STG_A(0, 0, 1);   // s2
  STG_B(0, 0, 2); STG_B(0, 0, 3);   // s3
  STG_A(0, 0, 2); STG_A(0, 0, 3);   // s4
  SB0(); VMW4(); BARF();            // s1,s2(0) landed; {s3,s4(0)} in flight

  for (int t = 0; t < nt - 1; ++t) {
    const int cur = t & 1, nxt = cur ^ 1;
    const int kn = (t + 1) << 6;
    // P1: reads s1,s2(t); stages s1,s2(t+1); wait retires s3(t)
    RD_AF(cur, 0);
    RD_BF(cur, 0, b0s);
    STG_B(nxt, kn, 0); STG_B(nxt, kn, 1);
    STG_A(nxt, kn, 0); STG_A(nxt, kn, 1);
    SB0(); VMW6(); BARF();
    MFMA16(0, 0, b0s);
    BARF();
    // P2: reads s3(t); stages s3(t+1); wait retires s4(t)
    RD_BF(cur, 2, bfr);
    STG_B(nxt, kn, 2); STG_B(nxt, kn, 3);
    SB0(); VMW6(); BARF();
    MFMA16(0, 2, bfr);
    BARF();
    // P3: reads s4(t); stages s4(t+1); no wait
    RD_AF(cur, 4);
    STG_A(nxt, kn, 2); STG_A(nxt, kn, 3);
    BARF();
    MFMA16(4, 2, bfr);
    BARF();
    // P4: register B-frags; wait retires s1,s2(t+1)
    SB0(); VMW4(); BARF();
    MFMA16(4, 0, b0s);
    BARF();
  }
  {  // peeled last tile
    const int cur = (nt - 1) & 1;
    RD_AF(cur, 0);
    RD_BF(cur, 0, b0s);
    SB0(); VMW2(); BARF();          // retire s3(last)
    MFMA16(0, 0, b0s);
    BARF();
    RD_BF(cur, 2, bfr);
    SB0(); VMW0(); BARF();          // retire s4(last)
    MFMA16(0, 2, bfr);
    BARF();
    RD_AF(cur, 4);
    BARF();
    MFMA16(4, 2, bfr);
    BARF();
    MFMA16(4, 0, b0s);
  }

#undef STG_A
#undef STG_B
#undef RD_AF
#undef RD_BF
#undef MFMA16

  // C/D layout: col = lane&15, row = quad*4 + r  [m89/m91 verified]
#pragma unroll
  for (int m = 0; m < 8; ++m)
#pragma unroll
    for (int r = 0; r < 4; ++r) {
      size_t row = bm + wm + m * 16 + quad * 4 + r;
#pragma unroll
      for (int n = 0; n < 4; ++n) {
        size_t col = bn + wn + n * 16 + lane15;
        C[row * NS + col] = f2b(acc[m][n][r]);
      }
    }
}

// ---------------- bf16 GEMM (proven 128^2): C fp32 = A * Bt^T ----------------
__global__ __launch_bounds__(256) void gemm_bt_out(
    const u16* __restrict__ A, const u16* __restrict__ Bt, float* __restrict__ C,
    int M, int N, int K) {
  __shared__ __align__(16) u16 As[128 * 64];
  __shared__ __align__(16) u16 Bs[128 * 64];
  const int tid = threadIdx.x;
  const int lane = tid & 63, wave = tid >> 6;
  const int lane15 = lane & 15, quad = lane >> 4;
  const int wm = (wave >> 1) * 64, wn = (wave & 1) * 64;
  const size_t bm = (size_t)blockIdx.y * 128, bn = (size_t)blockIdx.x * 128;
  const int sreg_row = lane >> 3;
  const int schunk = lane & 7;

  f32x4 acc[4][4] = {};

  for (int k0 = 0; k0 < K; k0 += 64) {
#pragma unroll
    for (int i = 0; i < 4; ++i) {
      const int reg = wave * 4 + i;
      const int row = reg * 8 + sreg_row;
      const int gc = schunk ^ (row & 7);
      GLOAD_LDS16(A + (bm + row) * (size_t)K + k0 + gc * 8, &As[reg * 512]);
      GLOAD_LDS16(Bt + (bn + row) * (size_t)K + k0 + gc * 8, &Bs[reg * 512]);
    }
    __syncthreads();
#pragma unroll
    for (int kk = 0; kk < 64; kk += 32) {
      const int cb = kk >> 3;
      bf16x8 af[4], bfr[4];
#pragma unroll
      for (int mt = 0; mt < 4; ++mt) {
        const int row = wm + mt * 16 + lane15;
        af[mt] = *(const bf16x8*)&As[row * 64 + (((cb + quad) ^ (lane15 & 7)) * 8)];
      }
#pragma unroll
      for (int nt = 0; nt < 4; ++nt) {
        const int row = wn + nt * 16 + lane15;
        bfr[nt] = *(const bf16x8*)&Bs[row * 64 + (((cb + quad) ^ (lane15 & 7)) * 8)];
      }
#pragma unroll
      for (int mt = 0; mt < 4; ++mt)
#pragma unroll
        for (int nt = 0; nt < 4; ++nt)
          acc[mt][nt] = __builtin_amdgcn_mfma_f32_16x16x32_bf16(
              af[mt], bfr[nt], acc[mt][nt], 0, 0, 0);
    }
    __syncthreads();
  }
#pragma unroll
  for (int mt = 0; mt < 4; ++mt)
#pragma unroll
    for (int r = 0; r < 4; ++r) {
      size_t row = bm + wm + mt * 16 + quad * 4 + r;
#pragma unroll
      for (int nt = 0; nt < 4; ++nt) {
        size_t col = bn + wn + nt * 16 + lane15;
        C[row * N + col] = acc[mt][nt][r];
      }
    }
}

// ---------------- RoPE in-place on Q,K of qkv [S][3D] -----------------------
__global__ __launch_bounds__(256) void rope_kernel(u16* __restrict__ qkv) {
  int idx = blockIdx.x * 256 + threadIdx.x;  // S*2048 pair-threads
  int s = idx >> 11;
  int p = idx & 2047;
  int h = p >> 6, j = p & 63;
  float freq = exp2f(-(float)j * 0.20762050593046015f);  // 10000^(-j/64)
  float ang = (float)s * freq;
  float sn = __sinf(ang), cs = __cosf(ang);
  size_t base = (size_t)s * LDQKV + h * HDIM + 2 * j;
  u32 q = *(const u32*)(qkv + base);
  float q0 = b2f((u16)(q & 0xffff)), q1 = b2f((u16)(q >> 16));
  u32 qo = (u32)f2b(q0 * cs - q1 * sn) | ((u32)f2b(q0 * sn + q1 * cs) << 16);
  *(u32*)(qkv + base) = qo;
  u32 k = *(const u32*)(qkv + base + D_MODEL);
  float k0 = b2f((u16)(k & 0xffff)), k1 = b2f((u16)(k >> 16));
  u32 ko = (u32)f2b(k0 * cs - k1 * sn) | ((u32)f2b(k0 * sn + k1 * cs) << 16);
  *(u32*)(qkv + base + D_MODEL) = ko;
}

// ---------------- V section of qkv -> vt[h][d][s] ---------------------------
__global__ __launch_bounds__(256) void transpose_v(
    const u16* __restrict__ qkv, u16* __restrict__ vt) {
  __shared__ u16 tile[64][65];
  const int s0 = blockIdx.x * 64, d0 = blockIdx.y * 64, h = blockIdx.z;
  const int tid = threadIdx.x;
  const int tr = tid >> 3, tc = (tid & 7) * 8;
#pragma unroll
  for (int p = 0; p < 2; ++p) {
    U16x8 u;
    u.v = *(const uint4*)(qkv + (size_t)(s0 + p * 32 + tr) * LDQKV + 2 * D_MODEL +
                          h * HDIM + d0 + tc);
    u16* t = &tile[p * 32 + tr][tc];
#pragma unroll
    for (int j = 0; j < 8; ++j) t[j] = u.u[j];
  }
  __syncthreads();
  const int dd = tid >> 3, ss = (tid & 7) * 8;
#pragma unroll
  for (int p = 0; p < 2; ++p) {
    U16x8 u;
#pragma unroll
    for (int j = 0; j < 8; ++j) u.u[j] = tile[ss + j][p * 32 + dd];
    *(uint4*)(vt + (size_t)h * HDIM * S_LEN + (size_t)(d0 + p * 32 + dd) * S_LEN +
              s0 + ss) = u.v;
  }
}

// ---------------- Flash attention (non-causal, fixed-max softmax) -----------
// Round-0 proven version: global_load_lds staging, ~107 us.
__global__ __launch_bounds__(256, 2) void attn_kernel(
    const u16* __restrict__ qkv, const u16* __restrict__ vt, u16* __restrict__ ctx) {
  __shared__ __align__(16) u16 Ks[64 * 128];    // [kpos][d], XOR-swizzled 16B chunks
  __shared__ __align__(16) u16 Vs[128 * 64];    // [d][kpos], XOR-swizzled
  __shared__ __align__(16) u16 Ps[4][32 * 72];  // per-wave P, [q][kpos], stride 72
  const int h = blockIdx.y, qt = blockIdx.x;
  const int tid = threadIdx.x;
  const int lane = tid & 63, wave = tid >> 6;
  const int lane15 = lane & 15, quad = lane >> 4;
  const int q0 = qt * 128 + wave * 32;

  bf16x8 aq[2][4];
#pragma unroll
  for (int mi = 0; mi < 2; ++mi)
#pragma unroll
    for (int kt = 0; kt < 4; ++kt)
      aq[mi][kt] = *(const bf16x8*)(qkv + (size_t)(q0 + mi * 16 + lane15) * LDQKV +
                                    h * HDIM + kt * 32 + quad * 8);

  f32x4 o[2][8] = {};
  float lsum[2][4] = {};

  const int krow_off = wave * 16 + (lane >> 4);  // + i*4
  const int kslot = lane & 15;
  const int vrow_off = wave * 32 + (lane >> 3);  // + i*8
  const int vslot = lane & 7;
  const u16* kbase = qkv + D_MODEL + h * HDIM;
  const u16* vbase = vt + (size_t)h * HDIM * S_LEN;
  const float cexp = 0.12751879523243985f;  // log2(e)/sqrt(128)

  for (int kv0 = 0; kv0 < S_LEN; kv0 += 64) {
#pragma unroll
    for (int i = 0; i < 4; ++i) {
      const int krow = krow_off + i * 4;            // 0..63
      const int kgc = kslot ^ (krow & 7);
      GLOAD_LDS16(kbase + (size_t)(kv0 + krow) * LDQKV + kgc * 8,
                  &Ks[(wave * 16 + i * 4) * 128]);
      const int vrow = vrow_off + i * 8;            // 0..127 (d index)
      const int vgc = vslot ^ (vrow & 7);
      GLOAD_LDS16(vbase + (size_t)vrow * S_LEN + kv0 + vgc * 8,
                  &Vs[(wave * 32 + i * 8) * 64]);
    }
    __syncthreads();

    // S = Q K^T
    f32x4 sf[2][4] = {};
#pragma unroll
    for (int nt = 0; nt < 4; ++nt) {
      bf16x8 bk[4];
#pragma unroll
      for (int kt = 0; kt < 4; ++kt)
        bk[kt] = *(const bf16x8*)&Ks[(nt * 16 + lane15) * 128 +
                                     (((kt * 4 + quad) ^ (lane15 & 7)) * 8)];
#pragma unroll
      for (int kt = 0; kt < 4; ++kt) {
        sf[0][nt] = __builtin_amdgcn_mfma_f32_16x16x32_bf16(aq[0][kt], bk[kt], sf[0][nt], 0, 0, 0);
        sf[1][nt] = __builtin_amdgcn_mfma_f32_16x16x32_bf16(aq[1][kt], bk[kt], sf[1][nt], 0, 0, 0);
      }
    }

    // p = exp2(s*log2e/sqrt(HD)); per-lane l partials; P -> LDS (C->A layout)
#pragma unroll
    for (int mi = 0; mi < 2; ++mi)
#pragma unroll
      for (int nt = 0; nt < 4; ++nt)
#pragma unroll
        for (int r = 0; r < 4; ++r) {
          float pv = exp2f(sf[mi][nt][r] * cexp);
          lsum[mi][r] += pv;
          Ps[wave][(mi * 16 + quad * 4 + r) * 72 + nt * 16 + lane15] = f2b(pv);
        }

    // O += P * V
#pragma unroll
    for (int kt2 = 0; kt2 < 2; ++kt2) {
      bf16x8 ap0 = *(const bf16x8*)&Ps[wave][(lane15) * 72 + kt2 * 32 + quad * 8];
      bf16x8 ap1 = *(const bf16x8*)&Ps[wave][(16 + lane15) * 72 + kt2 * 32 + quad * 8];
#pragma unroll
      for (int nt2 = 0; nt2 < 8; ++nt2) {
        bf16x8 bv = *(const bf16x8*)&Vs[(nt2 * 16 + lane15) * 64 +
                                        (((kt2 * 4 + quad) ^ (lane15 & 7)) * 8)];
        o[0][nt2] = __builtin_amdgcn_mfma_f32_16x16x32_bf16(ap0, bv, o[0][nt2], 0, 0, 0);
        o[1][nt2] = __builtin_amdgcn_mfma_f32_16x16x32_bf16(ap1, bv, o[1][nt2], 0, 0, 0);
      }
    }
    __syncthreads();
  }

#pragma unroll
  for (int mi = 0; mi < 2; ++mi)
#pragma unroll
    for (int r = 0; r < 4; ++r) {
      float l = lsum[mi][r];
      l += __shfl_xor(l, 1);
      l += __shfl_xor(l, 2);
      l += __shfl_xor(l, 4);
      l += __shfl_xor(l, 8);
      float inv = 1.0f / l;
      size_t row = q0 + mi * 16 + quad * 4 + r;
#pragma unroll
      for (int nt2 = 0; nt2 < 8; ++nt2)
        ctx[row * D_MODEL + h * HDIM + nt2 * 16 + lane15] = f2b(o[mi][nt2][r] * inv);
    }
}

// ---------------------------------------------------------------------------
extern "C" void kernel_launch(void* const* d_in, const int* in_sizes, int n_in,
                              void* d_out, int out_size, void* d_ws, size_t ws_size,
                              hipStream_t stream) {
  const float* hs    = (const float*)d_in[0];  // [2048][4096]
  const float* w_qkv = (const float*)d_in[1];  // [4096][12288]
  const float* wo    = (const float*)d_in[2];  // [4096][4096]
  float* out = (float*)d_out;

  // workspace layout (208 MB total)
  char* w = (char*)d_ws;
  u16* hsb   = (u16*)(w);                        // 16 MB  bf16 hidden [2048][4096]
  u16* wqkvT = (u16*)(w + (16u  << 20));         // 96 MB  bf16 w_qkv^T [12288][4096]
  u16* woT   = (u16*)(w + (112u << 20));         // 32 MB  bf16 wo^T [4096][4096]
  u16* qkvb  = (u16*)(w + (144u << 20));         // 48 MB  bf16 qkv [2048][12288]
  u16* vt    = (u16*)(w + (192u << 20));         // 16 MB  bf16 vt [32][128][2048]
  u16* ctx   = hsb;  // reuse: hsb consumed by gemm1 before attn writes ctx

  convert_f32_bf16<<<4096, 256, 0, stream>>>(hs, hsb);
  tconv<<<dim3(12288 / 64, 4096 / 64), 256, 0, stream>>>(w_qkv, wqkvT, 4096, 12288);
  tconv<<<dim3(4096 / 64, 4096 / 64), 256, 0, stream>>>(wo, woT, 4096, 4096);

  // gemm1 as two half-N launches (attribution + identical packing):
  gemm256v3_qkv<<<dim3(24, 8), 512, 0, stream>>>(
      hsb, wqkvT, qkvb, 2048, 12288, 4096);
  gemm256v3_qkv<<<dim3(24, 8), 512, 0, stream>>>(
      hsb, wqkvT + (size_t)6144 * 4096, qkvb + 6144, 2048, 12288, 4096);

  rope_kernel<<<(S_LEN * 2048) / 256, 256, 0, stream>>>(qkvb);
  transpose_v<<<dim3(32, 2, 32), 256, 0, stream>>>(qkvb, vt);
  attn_kernel<<<dim3(16, 32), 256, 0, stream>>>(qkvb, vt, ctx);

  gemm_bt_out<<<dim3(4096 / 128, 2048 / 128), 256, 0, stream>>>(
      ctx, woT, out, 2048, 4096, 4096);
}